// Round 1
// baseline (334.274 us; speedup 1.0000x reference)
//
#include <hip/hip_runtime.h>
#include <cmath>

// ---------------------------------------------------------------------------
// CrossAttention: B=4, N=1024, C=1024, H=16, HD=64
//   q = x@Wq ; kv = k_in@Wkv ; p = softmax(q k^T /8); z = p*a; w = softmax(z)
//   out = (w@v)@Wproj + b
// Numerical design: z = p*a in [0,~0.01] => second softmax near-uniform =>
// q/k/score errors damped ~1e4x. Precision spent on: v (3-term compensated
// bf16 GEMM), PV (centered: out=(SumV + expm1(z)@v)/E), proj (3-term).
// ---------------------------------------------------------------------------

#define Bb 4
#define Nn 1024
#define Cc 1024
#define Hh 16
#define HD 64
#define BN 4096
static constexpr float SCALE = 0.125f;

typedef unsigned short u16;
typedef short bf16x8 __attribute__((ext_vector_type(8)));
typedef float f32x4 __attribute__((ext_vector_type(4)));
typedef __attribute__((address_space(1))) const void* gptr_t;
typedef __attribute__((address_space(3))) void* lptr_t;

__device__ __forceinline__ u16 f2b(float f) {
  union { float f; unsigned u; } x; x.f = f;
  unsigned u = x.u;
  return (u16)((u + 0x7FFFu + ((u >> 16) & 1u)) >> 16);
}
__device__ __forceinline__ float b2f(u16 h) {
  union { unsigned u; float f; } x; x.u = ((unsigned)h) << 16;
  return x.f;
}

// ---------------- prep: bf16 + hi/lo splits, transposed weights -------------
__global__ __launch_bounds__(256) void prep_big(
    const float* __restrict__ x, const float* __restrict__ kin,
    u16* __restrict__ xh, u16* __restrict__ kinh, u16* __restrict__ kinl) {
  int i = blockIdx.x * 256 + threadIdx.x;              // 4M threads exact
  xh[i] = f2b(x[i]);
  float v = kin[i];
  u16 hh = f2b(v);
  kinh[i] = hh;
  kinl[i] = f2b(v - b2f(hh));
}

__global__ __launch_bounds__(256) void prep_w(
    const float* __restrict__ Wq, const float* __restrict__ Wkv, const float* __restrict__ Wp,
    u16* __restrict__ WqT, u16* __restrict__ WkT, u16* __restrict__ WvTh, u16* __restrict__ WvTl,
    u16* __restrict__ WpTh, u16* __restrict__ WpTl) {
  int j = blockIdx.x * 256 + threadIdx.x;              // 1M threads; j=(o,i)
  int o = j >> 10, i = j & 1023;
  WqT[j] = f2b(Wq[(size_t)i * 1024 + o]);
  WkT[j] = f2b(Wkv[(size_t)i * 2048 + o]);
  float wv = Wkv[(size_t)i * 2048 + 1024 + o];
  u16 hh = f2b(wv);
  WvTh[j] = hh; WvTl[j] = f2b(wv - b2f(hh));
  float wp = Wp[(size_t)i * 1024 + o];
  hh = f2b(wp);
  WpTh[j] = hh; WpTl[j] = f2b(wp - b2f(hh));
}

// ---------------- plain bf16 GEMM (A[M][K] x Bt[N][K]) -> q_b/k_b bf16 ------
// 128x128 tile, 4 waves (2x2 of 64x64), BK=32, global_load_lds width 16.
__global__ __launch_bounds__(256) void gemm_qk(
    const u16* __restrict__ A, const u16* __restrict__ Bt, u16* __restrict__ dsth) {
  constexpr int K = 1024;
  __shared__ u16 As[4096];
  __shared__ u16 Bs[4096];
  const int tid = threadIdx.x;
  const int wave = tid >> 6, lane = tid & 63;
  const int l15 = lane & 15, l4 = lane >> 4;
  const int m0 = blockIdx.x * 128, n0 = blockIdx.y * 128;
  const int wr = wave >> 1, wc = wave & 1;
  const int srow = wave * 32 + (lane >> 2);
  const int scol = (lane & 3) * 8;
  f32x4 acc[4][4] = {};
  const u16* gA = A + (size_t)(m0 + srow) * K + scol;
  const u16* gB = Bt + (size_t)(n0 + srow) * K + scol;
  u16* lA0 = As + (wave * 2 + 0) * 512;
  u16* lA1 = As + (wave * 2 + 1) * 512;
  u16* lB0 = Bs + (wave * 2 + 0) * 512;
  u16* lB1 = Bs + (wave * 2 + 1) * 512;
  for (int kt = 0; kt < K; kt += 32) {
    __syncthreads();
    __builtin_amdgcn_global_load_lds((gptr_t)(gA + kt),            (lptr_t)lA0, 16, 0, 0);
    __builtin_amdgcn_global_load_lds((gptr_t)(gA + kt + 16 * K),   (lptr_t)lA1, 16, 0, 0);
    __builtin_amdgcn_global_load_lds((gptr_t)(gB + kt),            (lptr_t)lB0, 16, 0, 0);
    __builtin_amdgcn_global_load_lds((gptr_t)(gB + kt + 16 * K),   (lptr_t)lB1, 16, 0, 0);
    __syncthreads();
    bf16x8 af[4], bf_[4];
    #pragma unroll
    for (int i = 0; i < 4; ++i)
      af[i] = *(const bf16x8*)(As + (wr * 64 + i * 16 + l15) * 32 + l4 * 8);
    #pragma unroll
    for (int i = 0; i < 4; ++i)
      bf_[i] = *(const bf16x8*)(Bs + (wc * 64 + i * 16 + l15) * 32 + l4 * 8);
    #pragma unroll
    for (int mi = 0; mi < 4; ++mi)
      #pragma unroll
      for (int ni = 0; ni < 4; ++ni)
        acc[mi][ni] = __builtin_amdgcn_mfma_f32_16x16x32_bf16(af[mi], bf_[ni], acc[mi][ni], 0, 0, 0);
  }
  // epilogue: write bf16 into [b][h][n][d]
  #pragma unroll
  for (int mi = 0; mi < 4; ++mi) {
    #pragma unroll
    for (int ni = 0; ni < 4; ++ni) {
      #pragma unroll
      for (int r = 0; r < 4; ++r) {
        const int grow = m0 + wr * 64 + mi * 16 + l4 * 4 + r;    // b*N+n
        const int gcol = n0 + wc * 64 + ni * 16 + l15;           // h*64+d
        const int bb = grow >> 10, n = grow & 1023, hh = gcol >> 6, d = gcol & 63;
        dsth[(((size_t)(bb * Hh + hh)) * Nn + n) * HD + d] = f2b(acc[mi][ni][r]);
      }
    }
  }
}

// ------------- fused 3-term compensated GEMM: Ah*Bh + Ah*Bl + Al*Bh ---------
// EPI 0: V  -> write vT f32 [b][h][d][n] + vT bf16
// EPI 1: OUT-> write d_out f32 [b*N+n][c] with bias
template <int EPI>
__global__ __launch_bounds__(256) void gemm3_bt(
    const u16* __restrict__ Ah, const u16* __restrict__ Al,
    const u16* __restrict__ Bh, const u16* __restrict__ Bl,
    float* __restrict__ dstf, u16* __restrict__ dsth, const float* __restrict__ bias) {
  constexpr int K = 1024;
  __shared__ u16 sAh[4096], sAl[4096], sBh[4096], sBl[4096];
  const int tid = threadIdx.x;
  const int wave = tid >> 6, lane = tid & 63;
  const int l15 = lane & 15, l4 = lane >> 4;
  const int m0 = blockIdx.x * 128, n0 = blockIdx.y * 128;
  const int wr = wave >> 1, wc = wave & 1;
  const int srow = wave * 32 + (lane >> 2);
  const int scol = (lane & 3) * 8;
  f32x4 acc[4][4] = {};
  const u16* gAh = Ah + (size_t)(m0 + srow) * K + scol;
  const u16* gAl = Al + (size_t)(m0 + srow) * K + scol;
  const u16* gBh = Bh + (size_t)(n0 + srow) * K + scol;
  const u16* gBl = Bl + (size_t)(n0 + srow) * K + scol;
  const int eoff = (wave * 2) * 512;
  for (int kt = 0; kt < K; kt += 32) {
    __syncthreads();
    __builtin_amdgcn_global_load_lds((gptr_t)(gAh + kt),          (lptr_t)(sAh + eoff), 16, 0, 0);
    __builtin_amdgcn_global_load_lds((gptr_t)(gAh + kt + 16 * K), (lptr_t)(sAh + eoff + 512), 16, 0, 0);
    __builtin_amdgcn_global_load_lds((gptr_t)(gAl + kt),          (lptr_t)(sAl + eoff), 16, 0, 0);
    __builtin_amdgcn_global_load_lds((gptr_t)(gAl + kt + 16 * K), (lptr_t)(sAl + eoff + 512), 16, 0, 0);
    __builtin_amdgcn_global_load_lds((gptr_t)(gBh + kt),          (lptr_t)(sBh + eoff), 16, 0, 0);
    __builtin_amdgcn_global_load_lds((gptr_t)(gBh + kt + 16 * K), (lptr_t)(sBh + eoff + 512), 16, 0, 0);
    __builtin_amdgcn_global_load_lds((gptr_t)(gBl + kt),          (lptr_t)(sBl + eoff), 16, 0, 0);
    __builtin_amdgcn_global_load_lds((gptr_t)(gBl + kt + 16 * K), (lptr_t)(sBl + eoff + 512), 16, 0, 0);
    __syncthreads();
    bf16x8 fah[4], fal[4], fbh[4], fbl[4];
    #pragma unroll
    for (int i = 0; i < 4; ++i) {
      const int ra = (wr * 64 + i * 16 + l15) * 32 + l4 * 8;
      const int rb = (wc * 64 + i * 16 + l15) * 32 + l4 * 8;
      fah[i] = *(const bf16x8*)(sAh + ra);
      fal[i] = *(const bf16x8*)(sAl + ra);
      fbh[i] = *(const bf16x8*)(sBh + rb);
      fbl[i] = *(const bf16x8*)(sBl + rb);
    }
    #pragma unroll
    for (int mi = 0; mi < 4; ++mi) {
      #pragma unroll
      for (int ni = 0; ni < 4; ++ni) {
        acc[mi][ni] = __builtin_amdgcn_mfma_f32_16x16x32_bf16(fah[mi], fbh[ni], acc[mi][ni], 0, 0, 0);
        acc[mi][ni] = __builtin_amdgcn_mfma_f32_16x16x32_bf16(fah[mi], fbl[ni], acc[mi][ni], 0, 0, 0);
        acc[mi][ni] = __builtin_amdgcn_mfma_f32_16x16x32_bf16(fal[mi], fbh[ni], acc[mi][ni], 0, 0, 0);
      }
    }
  }
  #pragma unroll
  for (int mi = 0; mi < 4; ++mi) {
    #pragma unroll
    for (int ni = 0; ni < 4; ++ni) {
      #pragma unroll
      for (int r = 0; r < 4; ++r) {
        const int grow = m0 + wr * 64 + mi * 16 + l4 * 4 + r;
        const int gcol = n0 + wc * 64 + ni * 16 + l15;
        const float v = acc[mi][ni][r];
        if constexpr (EPI == 0) {
          const int bb = grow >> 10, n = grow & 1023, hh = gcol >> 6, d = gcol & 63;
          const size_t o = (((size_t)(bb * Hh + hh)) * HD + d) * Nn + n;
          dstf[o] = v;
          dsth[o] = f2b(v);
        } else {
          dstf[(size_t)grow * Cc + gcol] = v + bias[gcol];
        }
      }
    }
  }
}

// ---------------- SumV[b][h][d] = sum_m v[m][d] (fp32) ----------------------
__global__ __launch_bounds__(256) void sumv_kernel(const float* __restrict__ vtf,
                                                   float* __restrict__ sv) {
  const int bh = blockIdx.x >> 2, d16 = blockIdx.x & 3;
  const int t = threadIdx.x;
  const int d = d16 * 16 + (t >> 4), part = t & 15;
  const float* src = vtf + ((size_t)bh * HD + d) * Nn + part * 64;
  float s = 0.f;
  #pragma unroll
  for (int i = 0; i < 64; i += 4) {
    f32x4 v = *(const f32x4*)(src + i);
    s += v[0] + v[1] + v[2] + v[3];
  }
  s += __shfl_xor(s, 1, 64);
  s += __shfl_xor(s, 2, 64);
  s += __shfl_xor(s, 4, 64);
  s += __shfl_xor(s, 8, 64);
  if (part == 0) sv[(size_t)bh * HD + d] = s;
}

// ---------------- fused double-softmax attention ----------------------------
// block = (b,h,qt): 16 q-rows; 4 waves. Single score pass, c=exp(s) cached in
// LDS (bf16, padded), then delta=expm1(c*a/L) in-place, then PV via MFMA.
__global__ __launch_bounds__(256) void attn_kernel(
    const u16* __restrict__ qb, const u16* __restrict__ kb,
    const u16* __restrict__ vtb, const float* __restrict__ sv,
    const float* __restrict__ af, u16* __restrict__ aoh, u16* __restrict__ aol) {
  __shared__ u16 c_lds[16][1032];     // exp(s) then expm1(z), padded stride
  __shared__ u16 kv_lds[128 * 72];    // k view [128][72]; v view [64][136]
  __shared__ u16 q_lds[16][72];
  __shared__ float Lp_lds[4][16];
  __shared__ float Ep_lds[4][16];
  __shared__ float L_arr[16];

  const int tid = threadIdx.x;
  const int wave = tid >> 6, lane = tid & 63;
  const int l15 = lane & 15, l4 = lane >> 4;
  const int bid = blockIdx.x;
  const int qt = bid & 63, h = (bid >> 6) & 15, b = bid >> 10;
  const size_t bh = (size_t)(b * Hh + h);
  const u16* qg = qb + (bh * Nn + qt * 16) * HD;
  const u16* kg = kb + bh * Nn * HD;
  const u16* vg = vtb + bh * HD * Nn;

  // stage q tile [16][64]
  {
    const int row = tid >> 4, d0 = (tid & 15) * 4;
    *(uint2*)&q_lds[row][d0] = *(const uint2*)&qg[row * HD + d0];
  }
  __syncthreads();

  // phase 1: scores -> c=exp(s*SCALE), accumulate L
  float Lp[4] = {0.f, 0.f, 0.f, 0.f};
  for (int mt = 0; mt < 8; ++mt) {
    {
      const int row = tid >> 1, half = tid & 1;
      const u16* src = kg + ((size_t)(mt * 128 + row)) * HD + half * 32;
      u16* dst = kv_lds + row * 72 + half * 32;
      *(uint4*)(dst + 0)  = *(const uint4*)(src + 0);
      *(uint4*)(dst + 8)  = *(const uint4*)(src + 8);
      *(uint4*)(dst + 16) = *(const uint4*)(src + 16);
      *(uint4*)(dst + 24) = *(const uint4*)(src + 24);
    }
    __syncthreads();
    #pragma unroll
    for (int cf = 0; cf < 2; ++cf) {
      f32x4 acc = {0.f, 0.f, 0.f, 0.f};
      const int mloc = wave * 32 + cf * 16 + l15;
      #pragma unroll
      for (int ks = 0; ks < 2; ++ks) {
        bf16x8 a = *(const bf16x8*)&q_lds[l15][ks * 32 + l4 * 8];
        bf16x8 bb = *(const bf16x8*)&kv_lds[mloc * 72 + ks * 32 + l4 * 8];
        acc = __builtin_amdgcn_mfma_f32_16x16x32_bf16(a, bb, acc, 0, 0, 0);
      }
      #pragma unroll
      for (int r = 0; r < 4; ++r) {
        const float c = __expf(acc[r] * SCALE);
        Lp[r] += c;
        c_lds[l4 * 4 + r][mt * 128 + wave * 32 + cf * 16 + l15] = f2b(c);
      }
    }
    __syncthreads();
  }
  #pragma unroll
  for (int r = 0; r < 4; ++r) {
    float v = Lp[r];
    v += __shfl_xor(v, 1, 64);
    v += __shfl_xor(v, 2, 64);
    v += __shfl_xor(v, 4, 64);
    v += __shfl_xor(v, 8, 64);
    if (l15 == 0) Lp_lds[wave][l4 * 4 + r] = v;
  }
  __syncthreads();
  if (tid < 16) L_arr[tid] = Lp_lds[0][tid] + Lp_lds[1][tid] + Lp_lds[2][tid] + Lp_lds[3][tid];
  __syncthreads();

  // phase 2: delta = expm1(c/L * a) in place (bf16), accumulate E partials
  #pragma unroll
  for (int rh = 0; rh < 2; ++rh) {
    const int row = rh * 8 + (lane >> 3);
    const int mw = wave * 256 + (lane & 7) * 32;
    const float linv = 1.0f / L_arr[row];
    const float* ag = af + ((size_t)b * Nn + qt * 16 + row) * Nn + mw;
    float ep = 0.f;
    #pragma unroll
    for (int cc = 0; cc < 4; ++cc) {
      bf16x8 cv = *(const bf16x8*)&c_lds[row][mw + cc * 8];
      f32x4 a0 = *(const f32x4*)(ag + cc * 8);
      f32x4 a1 = *(const f32x4*)(ag + cc * 8 + 4);
      bf16x8 dv;
      #pragma unroll
      for (int j = 0; j < 8; ++j) {
        const float cval = b2f((u16)cv[j]);
        const float aval = (j < 4) ? a0[j] : a1[j - 4];
        const float z = cval * linv * aval;
        const float dl = expm1f(z);
        ep += dl;
        dv[j] = (short)f2b(dl);
      }
      *(bf16x8*)&c_lds[row][mw + cc * 8] = dv;
    }
    ep += __shfl_xor(ep, 1, 64);
    ep += __shfl_xor(ep, 2, 64);
    ep += __shfl_xor(ep, 4, 64);
    if ((lane & 7) == 0) Ep_lds[wave][row] = ep;
  }
  __syncthreads();

  // phase 3: PV. out[16][64]; wave owns d-cols [wave*16, +16)
  f32x4 oacc = {0.f, 0.f, 0.f, 0.f};
  for (int mt = 0; mt < 8; ++mt) {
    {
      const int row = tid >> 2, qq = tid & 3;
      const u16* src = vg + (size_t)row * Nn + mt * 128 + qq * 32;
      u16* dst = kv_lds + row * 136 + qq * 32;
      *(uint4*)(dst + 0)  = *(const uint4*)(src + 0);
      *(uint4*)(dst + 8)  = *(const uint4*)(src + 8);
      *(uint4*)(dst + 16) = *(const uint4*)(src + 16);
      *(uint4*)(dst + 24) = *(const uint4*)(src + 24);
    }
    __syncthreads();
    #pragma unroll
    for (int ks = 0; ks < 4; ++ks) {
      bf16x8 a = *(const bf16x8*)&c_lds[l15][mt * 128 + ks * 32 + l4 * 8];
      bf16x8 bb = *(const bf16x8*)&kv_lds[(wave * 16 + l15) * 136 + ks * 32 + l4 * 8];
      oacc = __builtin_amdgcn_mfma_f32_16x16x32_bf16(a, bb, oacc, 0, 0, 0);
    }
    __syncthreads();
  }

  // epilogue: out = (SumV + sum(expm1*v)) / E ; write bf16 hi/lo for proj
  {
    const int d = wave * 16 + l15;
    const float svd = sv[bh * HD + d];
    #pragma unroll
    for (int r = 0; r < 4; ++r) {
      const int row = l4 * 4 + r;
      const float E = 1024.0f + Ep_lds[0][row] + Ep_lds[1][row] + Ep_lds[2][row] + Ep_lds[3][row];
      const float ov = (svd + oacc[r]) / E;
      const int n = qt * 16 + row;
      const size_t oi = ((size_t)b * Nn + n) * Cc + h * HD + d;
      const u16 hi = f2b(ov);
      aoh[oi] = hi;
      aol[oi] = f2b(ov - b2f(hi));
    }
  }
}

// ---------------------------------------------------------------------------
extern "C" void kernel_launch(void* const* d_in, const int* in_sizes, int n_in,
                              void* d_out, int out_size, void* d_ws, size_t ws_size,
                              hipStream_t stream) {
  (void)in_sizes; (void)n_in; (void)out_size; (void)ws_size;
  const float* x   = (const float*)d_in[0];
  const float* kin = (const float*)d_in[1];
  const float* af  = (const float*)d_in[2];
  const float* Wq  = (const float*)d_in[3];
  const float* Wkv = (const float*)d_in[4];
  const float* Wp  = (const float*)d_in[5];
  const float* bp  = (const float*)d_in[6];
  float* out = (float*)d_out;

  char* w = (char*)d_ws;
  auto take = [&](size_t bytes) { char* p = w; w += (bytes + 255) & ~(size_t)255; return p; };
  u16* WqT   = (u16*)take(2097152);
  u16* WkT   = (u16*)take(2097152);
  u16* WvTh  = (u16*)take(2097152);
  u16* WvTl  = (u16*)take(2097152);
  u16* WpTh  = (u16*)take(2097152);
  u16* WpTl  = (u16*)take(2097152);
  u16* xh    = (u16*)take(8388608);
  u16* kinh  = (u16*)take(8388608);
  u16* kinl  = (u16*)take(8388608);
  u16* qb    = (u16*)take(8388608);
  u16* kb    = (u16*)take(8388608);
  u16* vtb   = (u16*)take(8388608);
  float* vtf = (float*)take(16777216);
  float* sv  = (float*)take(16384);
  u16* aoh   = (u16*)take(8388608);
  u16* aol   = (u16*)take(8388608);

  prep_big<<<dim3(16384), dim3(256), 0, stream>>>(x, kin, xh, kinh, kinl);
  prep_w<<<dim3(4096), dim3(256), 0, stream>>>(Wq, Wkv, Wp, WqT, WkT, WvTh, WvTl, WpTh, WpTl);

  dim3 gg(32, 8), blk(256);
  gemm_qk<<<gg, blk, 0, stream>>>(xh, WqT, qb);
  gemm_qk<<<gg, blk, 0, stream>>>(kinh, WkT, kb);
  gemm3_bt<0><<<gg, blk, 0, stream>>>(kinh, kinl, WvTh, WvTl, vtf, vtb, nullptr);
  sumv_kernel<<<dim3(256), dim3(256), 0, stream>>>(vtf, sv);
  attn_kernel<<<dim3(4096), dim3(256), 0, stream>>>(qb, kb, vtb, sv, af, aoh, aol);
  gemm3_bt<1><<<gg, blk, 0, stream>>>(aoh, aol, WpTh, WpTl, out, nullptr, bp);
}